// Round 1
// baseline (2239.364 us; speedup 1.0000x reference)
//
#include <hip/hip_runtime.h>
#include <hip/hip_bf16.h>
#include <math.h>

#define BSZ 4
#define NSEQ 2048
#define CDIM 1024
#define NH 16
#define DH 64

// ---------------------------------------------------------------------------
// Kernel 1: qkv = x @ W_qkv + b_qkv, then RoPE on q,k; write Q,K,V [B,H,N,Dh]
// Tile: 64(M) x 64(N), K-step 16. 256 threads, 4x4 micro-tile each.
// N-tile of 64 == exactly one head of one of {q,k,v}, so the rotate_half
// partner (d +/- 32) lives inside this block's C tile in LDS.
// ---------------------------------------------------------------------------
__global__ __launch_bounds__(256) void qkv_rope_kernel(
    const float* __restrict__ x, const float* __restrict__ W,
    const float* __restrict__ bias, float* __restrict__ Q,
    float* __restrict__ K, float* __restrict__ V) {
  __shared__ float As[16][64];   // As[kk][m]
  __shared__ float Bs[16][64];   // Bs[kk][n]
  __shared__ float Cs[64][65];   // C tile for RoPE partner access
  const int tid = threadIdx.x;
  const int tx = tid & 15, ty = tid >> 4;
  const int m0 = blockIdx.y * 64;
  const int n0 = blockIdx.x * 64;
  const int lr = tid >> 2;          // 0..63  (A-tile row)
  const int lc = (tid & 3) * 4;     // 0,4,8,12 (A-tile col group)
  float acc[4][4] = {};
  const float* xrow = x + (size_t)(m0 + lr) * CDIM + lc;
  const float* wrow = W + (size_t)ty * 3072 + n0 + tx * 4;

  for (int k0 = 0; k0 < CDIM; k0 += 16) {
    float4 a4 = *(const float4*)(xrow + k0);
    float4 b4 = *(const float4*)(wrow + (size_t)k0 * 3072);
    __syncthreads();
    As[lc + 0][lr] = a4.x; As[lc + 1][lr] = a4.y;
    As[lc + 2][lr] = a4.z; As[lc + 3][lr] = a4.w;
    *(float4*)&Bs[ty][tx * 4] = b4;
    __syncthreads();
#pragma unroll
    for (int kk = 0; kk < 16; ++kk) {
      float4 av = *(const float4*)&As[kk][ty * 4];
      float4 bv = *(const float4*)&Bs[kk][tx * 4];
      float a[4] = {av.x, av.y, av.z, av.w};
      float b[4] = {bv.x, bv.y, bv.z, bv.w};
#pragma unroll
      for (int i = 0; i < 4; ++i)
#pragma unroll
        for (int j = 0; j < 4; ++j) acc[i][j] += a[i] * b[j];
    }
  }
  __syncthreads();
#pragma unroll
  for (int i = 0; i < 4; ++i)
#pragma unroll
    for (int j = 0; j < 4; ++j)
      Cs[ty * 4 + i][tx * 4 + j] = acc[i][j] + bias[n0 + tx * 4 + j];
  __syncthreads();

  const int which = n0 >> 10;      // 0=q 1=k 2=v
  const int h = (n0 >> 6) & 15;    // head index
#pragma unroll
  for (int i = 0; i < 4; ++i) {
    const int m = m0 + ty * 4 + i;
    const int b = m >> 11;         // /2048
    const int n = m & 2047;
    const size_t base = ((size_t)((b * NH + h) * NSEQ + n)) * DH;
#pragma unroll
    for (int j = 0; j < 4; ++j) {
      const int d = tx * 4 + j;
      const float val = Cs[ty * 4 + i][d];
      if (which == 2) {
        V[base + d] = val;
      } else {
        // inv_freq = 10000^(-(d%32)/32); theta = n * inv_freq
        const float invf = expf(-9.210340371976184f * ((float)(d & 31) * (1.0f / 32.0f)));
        const float theta = (float)n * invf;
        float sv, cv;
        sincosf(theta, &sv, &cv);
        const float partner = (d < 32) ? -Cs[ty * 4 + i][d + 32]
                                       :  Cs[ty * 4 + i][d - 32];
        const float o = val * cv + partner * sv;
        if (which == 0) Q[base + d] = o;
        else            K[base + d] = o;
      }
    }
  }
}

// ---------------------------------------------------------------------------
// Kernel 2: flash-style attention per (b*h, q-tile of 64). fp32.
// S = Q K^T * 0.125, online softmax (m,l in LDS), O += P V, out = O / l.
// Operands stored transposed in LDS so both sides of the FMA are b128 reads.
// ---------------------------------------------------------------------------
__global__ __launch_bounds__(256) void attn_kernel(
    const float* __restrict__ Q, const float* __restrict__ K,
    const float* __restrict__ V, float* __restrict__ AO) {
  __shared__ float QT[64][68];   // QT[kk][r]
  __shared__ float KT[64][68];   // KT[kk][c]
  __shared__ float Vs[64][64];   // Vs[key][d]
  __shared__ float ST[64][68];   // ST[key][r]  (S then P, transposed)
  __shared__ float mrow[64], lrow[64], arow[64], red[64][4];
  const int tid = threadIdx.x;
  const int tx = tid & 15, ty = tid >> 4;
  const int bh = blockIdx.y;           // 0..63
  const int q0 = blockIdx.x * 64;
  const float* Qb = Q + (size_t)bh * NSEQ * DH;
  const float* Kb = K + (size_t)bh * NSEQ * DH;
  const float* Vb = V + (size_t)bh * NSEQ * DH;

  {
    const int cg = (tid & 15) * 4, r0 = tid >> 4;
#pragma unroll
    for (int rep = 0; rep < 4; ++rep) {
      const int row = r0 + rep * 16;
      float4 q4 = *(const float4*)(Qb + (size_t)(q0 + row) * DH + cg);
      QT[cg + 0][row] = q4.x; QT[cg + 1][row] = q4.y;
      QT[cg + 2][row] = q4.z; QT[cg + 3][row] = q4.w;
    }
  }
  if (tid < 64) { mrow[tid] = -1e30f; lrow[tid] = 0.0f; }
  float O[4][4] = {};

  for (int kt = 0; kt < 32; ++kt) {
    const int k0 = kt * 64;
    __syncthreads();   // prior-iter readers done before overwriting KT/Vs/ST
    {
      const int cg = (tid & 15) * 4, r0 = tid >> 4;
#pragma unroll
      for (int rep = 0; rep < 4; ++rep) {
        const int row = r0 + rep * 16;
        float4 k4 = *(const float4*)(Kb + (size_t)(k0 + row) * DH + cg);
        float4 v4 = *(const float4*)(Vb + (size_t)(k0 + row) * DH + cg);
        KT[cg + 0][row] = k4.x; KT[cg + 1][row] = k4.y;
        KT[cg + 2][row] = k4.z; KT[cg + 3][row] = k4.w;
        *(float4*)&Vs[row][cg] = v4;
      }
    }
    __syncthreads();

    float acc[4][4] = {};
#pragma unroll 8
    for (int kk = 0; kk < 64; ++kk) {
      float4 qa = *(const float4*)&QT[kk][ty * 4];
      float4 kb = *(const float4*)&KT[kk][tx * 4];
      float a[4] = {qa.x, qa.y, qa.z, qa.w};
      float b[4] = {kb.x, kb.y, kb.z, kb.w};
#pragma unroll
      for (int i = 0; i < 4; ++i)
#pragma unroll
        for (int j = 0; j < 4; ++j) acc[i][j] += a[i] * b[j];
    }
#pragma unroll
    for (int i = 0; i < 4; ++i)
#pragma unroll
      for (int j = 0; j < 4; ++j)
        ST[tx * 4 + j][ty * 4 + i] = acc[i][j] * 0.125f;
    __syncthreads();

    {  // online softmax: 4 threads per row, 16 cols each
      const int row = tid >> 2, q = tid & 3;
      float lm = -1e30f;
#pragma unroll
      for (int c = q * 16; c < q * 16 + 16; ++c) lm = fmaxf(lm, ST[c][row]);
      red[row][q] = lm;
      __syncthreads();
      if (q == 0) {
        float mn = fmaxf(fmaxf(red[row][0], red[row][1]),
                         fmaxf(red[row][2], red[row][3]));
        mn = fmaxf(mn, mrow[row]);
        arow[row] = expf(mrow[row] - mn);
        mrow[row] = mn;
      }
      __syncthreads();
      const float mn = mrow[row];
      float ls = 0.0f;
#pragma unroll
      for (int c = q * 16; c < q * 16 + 16; ++c) {
        const float p = expf(ST[c][row] - mn);
        ST[c][row] = p;
        ls += p;
      }
      red[row][q] = ls;
      __syncthreads();
      if (q == 0)
        lrow[row] = lrow[row] * arow[row] +
                    red[row][0] + red[row][1] + red[row][2] + red[row][3];
      __syncthreads();
    }

#pragma unroll
    for (int i = 0; i < 4; ++i) {
      const float a = arow[ty * 4 + i];
#pragma unroll
      for (int j = 0; j < 4; ++j) O[i][j] *= a;
    }
#pragma unroll 8
    for (int kk = 0; kk < 64; ++kk) {
      float4 pa = *(const float4*)&ST[kk][ty * 4];
      float4 vb = *(const float4*)&Vs[kk][tx * 4];
      float a[4] = {pa.x, pa.y, pa.z, pa.w};
      float b[4] = {vb.x, vb.y, vb.z, vb.w};
#pragma unroll
      for (int i = 0; i < 4; ++i)
#pragma unroll
        for (int j = 0; j < 4; ++j) O[i][j] += a[i] * b[j];
    }
  }

  const int b = bh >> 4, h = bh & 15;
#pragma unroll
  for (int i = 0; i < 4; ++i) {
    const int n = q0 + ty * 4 + i;
    const float inv = 1.0f / lrow[ty * 4 + i];
    float4 o4;
    o4.x = O[i][0] * inv; o4.y = O[i][1] * inv;
    o4.z = O[i][2] * inv; o4.w = O[i][3] * inv;
    *(float4*)&AO[((size_t)(b * NSEQ + n)) * CDIM + h * DH + tx * 4] = o4;
  }
}

// ---------------------------------------------------------------------------
// Kernel 3: out = AO @ W_proj + b_proj.  Same GEMM structure, direct store.
// ---------------------------------------------------------------------------
__global__ __launch_bounds__(256) void proj_kernel(
    const float* __restrict__ A, const float* __restrict__ W,
    const float* __restrict__ bias, float* __restrict__ out) {
  __shared__ float As[16][64];
  __shared__ float Bs[16][64];
  const int tid = threadIdx.x;
  const int tx = tid & 15, ty = tid >> 4;
  const int m0 = blockIdx.y * 64;
  const int n0 = blockIdx.x * 64;
  const int lr = tid >> 2;
  const int lc = (tid & 3) * 4;
  float acc[4][4] = {};
  const float* arow = A + (size_t)(m0 + lr) * CDIM + lc;
  const float* wrow = W + (size_t)ty * CDIM + n0 + tx * 4;

  for (int k0 = 0; k0 < CDIM; k0 += 16) {
    float4 a4 = *(const float4*)(arow + k0);
    float4 b4 = *(const float4*)(wrow + (size_t)k0 * CDIM);
    __syncthreads();
    As[lc + 0][lr] = a4.x; As[lc + 1][lr] = a4.y;
    As[lc + 2][lr] = a4.z; As[lc + 3][lr] = a4.w;
    *(float4*)&Bs[ty][tx * 4] = b4;
    __syncthreads();
#pragma unroll
    for (int kk = 0; kk < 16; ++kk) {
      float4 av = *(const float4*)&As[kk][ty * 4];
      float4 bv = *(const float4*)&Bs[kk][tx * 4];
      float a[4] = {av.x, av.y, av.z, av.w};
      float b[4] = {bv.x, bv.y, bv.z, bv.w};
#pragma unroll
      for (int i = 0; i < 4; ++i)
#pragma unroll
        for (int j = 0; j < 4; ++j) acc[i][j] += a[i] * b[j];
    }
  }
#pragma unroll
  for (int i = 0; i < 4; ++i) {
    const int m = m0 + ty * 4 + i;
    float4 o4;
    o4.x = acc[i][0] + bias[n0 + tx * 4 + 0];
    o4.y = acc[i][1] + bias[n0 + tx * 4 + 1];
    o4.z = acc[i][2] + bias[n0 + tx * 4 + 2];
    o4.w = acc[i][3] + bias[n0 + tx * 4 + 3];
    *(float4*)&out[(size_t)m * CDIM + n0 + tx * 4] = o4;
  }
}

// ---------------------------------------------------------------------------
extern "C" void kernel_launch(void* const* d_in, const int* in_sizes, int n_in,
                              void* d_out, int out_size, void* d_ws, size_t ws_size,
                              hipStream_t stream) {
  const float* x     = (const float*)d_in[0];
  const float* Wqkv  = (const float*)d_in[1];
  const float* bqkv  = (const float*)d_in[2];
  const float* Wproj = (const float*)d_in[3];
  const float* bproj = (const float*)d_in[4];
  float* out = (float*)d_out;
  float* ws  = (float*)d_ws;

  const size_t per = (size_t)BSZ * NH * NSEQ * DH;  // 8,388,608 floats
  float* Q  = ws;
  float* K  = ws + per;
  float* V  = ws + 2 * per;
  float* AO = ws + 3 * per;  // [B,N,C] attention output, pre-projection

  // QKV GEMM + RoPE: grid (3072/64, 8192/64)
  qkv_rope_kernel<<<dim3(48, 128), 256, 0, stream>>>(x, Wqkv, bqkv, Q, K, V);
  // Attention: grid (2048/64 q-tiles, B*H)
  attn_kernel<<<dim3(32, 64), 256, 0, stream>>>(Q, K, V, AO);
  // Projection: grid (1024/64, 8192/64)
  proj_kernel<<<dim3(16, 128), 256, 0, stream>>>(AO, Wproj, bproj, out);
}

// Round 2
// 1172.126 us; speedup vs baseline: 1.9105x; 1.9105x over previous
//
#include <hip/hip_runtime.h>
#include <hip/hip_bf16.h>
#include <math.h>

#define BSZ 4
#define NSEQ 2048
#define CDIM 1024
#define NH 16
#define DH 64
#define KC 64   // keys per attention chunk

typedef _Float16 half8_t __attribute__((ext_vector_type(8)));
typedef _Float16 half4_t __attribute__((ext_vector_type(4)));
typedef float floatx4 __attribute__((ext_vector_type(4)));

// ---------------------------------------------------------------------------
// Kernel 1: qkv = x @ W_qkv + b_qkv (fp32 GEMM), RoPE on q,k in epilogue.
// Writes fp16: Qh [bh][n][64] (pre-scaled by 0.125*log2e), Kh [bh][n][64],
// Vh [bh][64][n] (TRANSPOSED: d-major so attention PV frags are contiguous).
// ---------------------------------------------------------------------------
__global__ __launch_bounds__(256) void qkv_rope_kernel(
    const float* __restrict__ x, const float* __restrict__ W,
    const float* __restrict__ bias, _Float16* __restrict__ Qh,
    _Float16* __restrict__ Kh, _Float16* __restrict__ Vh) {
  __shared__ float As[16][64];   // As[kk][m]
  __shared__ float Bs[16][64];   // Bs[kk][n]
  __shared__ float Cs[64][65];   // C tile (rows=n-local of seq, cols=d)
  const int tid = threadIdx.x;
  const int tx = tid & 15, ty = tid >> 4;
  const int m0 = blockIdx.y * 64;
  const int n0 = blockIdx.x * 64;
  const int lr = tid >> 2;
  const int lc = (tid & 3) * 4;
  float acc[4][4] = {};
  const float* xrow = x + (size_t)(m0 + lr) * CDIM + lc;
  const float* wrow = W + (size_t)ty * 3072 + n0 + tx * 4;

  for (int k0 = 0; k0 < CDIM; k0 += 16) {
    float4 a4 = *(const float4*)(xrow + k0);
    float4 b4 = *(const float4*)(wrow + (size_t)k0 * 3072);
    __syncthreads();
    As[lc + 0][lr] = a4.x; As[lc + 1][lr] = a4.y;
    As[lc + 2][lr] = a4.z; As[lc + 3][lr] = a4.w;
    *(float4*)&Bs[ty][tx * 4] = b4;
    __syncthreads();
#pragma unroll
    for (int kk = 0; kk < 16; ++kk) {
      float4 av = *(const float4*)&As[kk][ty * 4];
      float4 bv = *(const float4*)&Bs[kk][tx * 4];
      float a[4] = {av.x, av.y, av.z, av.w};
      float b[4] = {bv.x, bv.y, bv.z, bv.w};
#pragma unroll
      for (int i = 0; i < 4; ++i)
#pragma unroll
        for (int j = 0; j < 4; ++j) acc[i][j] += a[i] * b[j];
    }
  }
  __syncthreads();
#pragma unroll
  for (int i = 0; i < 4; ++i)
#pragma unroll
    for (int j = 0; j < 4; ++j)
      Cs[ty * 4 + i][tx * 4 + j] = acc[i][j] + bias[n0 + tx * 4 + j];
  __syncthreads();

  const int which = n0 >> 10;      // 0=q 1=k 2=v
  const int h = (n0 >> 6) & 15;    // head index
  const int b = m0 >> 11;          // batch (64-row tile never straddles)
  const int nbase = m0 & 2047;
  const int bh = b * NH + h;

  if (which == 2) {
    // V: transpose-write fp16 to Vh[bh][d][n]
    const int d = tid >> 2;
    const int ng = (tid & 3) * 16;
    half8_t v0, v1;
#pragma unroll
    for (int i = 0; i < 8; ++i) v0[i] = (_Float16)Cs[ng + i][d];
#pragma unroll
    for (int i = 0; i < 8; ++i) v1[i] = (_Float16)Cs[ng + 8 + i][d];
    _Float16* dst = Vh + ((size_t)bh * DH + d) * NSEQ + nbase + ng;
    *(half8_t*)dst = v0;
    *(half8_t*)(dst + 8) = v1;
  } else {
    _Float16* dst0 = (which == 0) ? Qh : Kh;
    const float qscale = 0.125f * 1.4426950408889634f;  // fold softmax scale+log2e into Q
#pragma unroll
    for (int i = 0; i < 4; ++i) {
      const int n = nbase + ty * 4 + i;
      half4_t o;
#pragma unroll
      for (int j = 0; j < 4; ++j) {
        const int d = tx * 4 + j;
        const float invf = expf(-9.210340371976184f * ((float)(d & 31) * (1.0f / 32.0f)));
        const float theta = (float)n * invf;
        float sv, cv;
        sincosf(theta, &sv, &cv);
        const float val = Cs[ty * 4 + i][d];
        const float partner = (d < 32) ? -Cs[ty * 4 + i][d + 32]
                                       :  Cs[ty * 4 + i][d - 32];
        float r = val * cv + partner * sv;
        if (which == 0) r *= qscale;
        o[j] = (_Float16)r;
      }
      *(half4_t*)(dst0 + ((size_t)bh * NSEQ + n) * DH + tx * 4) = o;
    }
  }
}

// ---------------------------------------------------------------------------
// Kernel 2: flash attention, fp16 MFMA (16x16x32), fp32 softmax/accum.
// Block = 4 waves; wave w owns q-rows [q0+16w, q0+16w+16).
// S^T = K * Q^T  (C layout: row=key-in-16, col=q -> softmax stats on lane&15)
// P -> wave-private LDS -> A-frag; O = P*V with V^T tiles in LDS.
// ---------------------------------------------------------------------------
__global__ __launch_bounds__(256) void attn_kernel(
    const _Float16* __restrict__ Qh, const _Float16* __restrict__ Kh,
    const _Float16* __restrict__ Vh, float* __restrict__ AO) {
  __shared__ char smem[27648];               // 27.0 KiB
  _Float16* Ks = (_Float16*)smem;            // [64][72]
  _Float16* Vt = (_Float16*)(smem + 9216);   // [64][72]  (rows = d, cols = key)
  _Float16* Ps = (_Float16*)(smem + 18432);  // [4 waves][16 q][72 keys]
  float* Os = (float*)smem;                  // [64][68]  (epilogue reuse)

  const int tid = threadIdx.x;
  const int lane = tid & 63;
  const int w = tid >> 6;
  const int m = lane & 15;
  const int quad = lane >> 4;
  const int bh = blockIdx.y;
  const int q0 = blockIdx.x * 64;

  const _Float16* Qb = Qh + (size_t)bh * NSEQ * DH;
  const _Float16* Kb = Kh + (size_t)bh * NSEQ * DH;
  const _Float16* Vb = Vh + (size_t)bh * DH * NSEQ;

  // Q fragments (B-operand: B[k=d=quad*8+j][n=q=lane&15]), 2 k-steps of 32
  const int qrow = q0 + w * 16 + m;
  half8_t qf0 = *(const half8_t*)(Qb + (size_t)qrow * DH + quad * 8);
  half8_t qf1 = *(const half8_t*)(Qb + (size_t)qrow * DH + 32 + quad * 8);

  float m_run = -1e30f, l_run = 0.0f;
  floatx4 O[4];
#pragma unroll
  for (int nb = 0; nb < 4; ++nb) O[nb] = (floatx4){0.f, 0.f, 0.f, 0.f};

  for (int ck = 0; ck < NSEQ / KC; ++ck) {
    const int k0 = ck * KC;
    __syncthreads();
    {  // stage K [key][d] and V^T [d][key] chunks, 16B per thread-group
      const _Float16* Kc = Kb + (size_t)k0 * DH;
      const _Float16* Vc = Vb + k0;
      int g = tid;
      int key = g >> 3, dg = g & 7;
      *(half8_t*)(Ks + key * 72 + dg * 8) = *(const half8_t*)(Kc + key * 64 + dg * 8);
      *(half8_t*)(Vt + key * 72 + dg * 8) = *(const half8_t*)(Vc + (size_t)key * NSEQ + dg * 8);
      g = tid + 256;
      key = g >> 3; dg = g & 7;
      *(half8_t*)(Ks + key * 72 + dg * 8) = *(const half8_t*)(Kc + key * 64 + dg * 8);
      *(half8_t*)(Vt + key * 72 + dg * 8) = *(const half8_t*)(Vc + (size_t)key * NSEQ + dg * 8);
    }
    __syncthreads();

    // S^T = K * Q^T : 4 key-subtiles of 16
    floatx4 st[4];
#pragma unroll
    for (int kt = 0; kt < 4; ++kt) {
      floatx4 a = (floatx4){0.f, 0.f, 0.f, 0.f};
      half8_t kf0 = *(half8_t*)(Ks + (kt * 16 + m) * 72 + quad * 8);
      half8_t kf1 = *(half8_t*)(Ks + (kt * 16 + m) * 72 + 32 + quad * 8);
      a = __builtin_amdgcn_mfma_f32_16x16x32_f16(kf0, qf0, a, 0, 0, 0);
      a = __builtin_amdgcn_mfma_f32_16x16x32_f16(kf1, qf1, a, 0, 0, 0);
      st[kt] = a;  // st[kt][r] = S^T[key=16kt+4quad+r][q=m]  (log2-domain)
    }

    // online softmax over this chunk (per q = lane&15, reduce across quads)
    float mx = -1e30f;
#pragma unroll
    for (int kt = 0; kt < 4; ++kt)
#pragma unroll
      for (int r = 0; r < 4; ++r) mx = fmaxf(mx, st[kt][r]);
    mx = fmaxf(mx, __shfl_xor(mx, 16, 64));
    mx = fmaxf(mx, __shfl_xor(mx, 32, 64));
    const float m_new = fmaxf(m_run, mx);
    const float alpha = __builtin_exp2f(m_run - m_new);
    m_run = m_new;
    float rs = 0.0f;
#pragma unroll
    for (int kt = 0; kt < 4; ++kt)
#pragma unroll
      for (int r = 0; r < 4; ++r) {
        const float pv = __builtin_exp2f(st[kt][r] - m_new);
        st[kt][r] = pv;
        rs += pv;
      }
    rs += __shfl_xor(rs, 16, 64);
    rs += __shfl_xor(rs, 32, 64);
    l_run = l_run * alpha + rs;

    // P -> LDS (wave-private; row q=m, 4 consecutive keys per b64 write)
    _Float16* Pw = Ps + w * 1152 + m * 72;
#pragma unroll
    for (int kt = 0; kt < 4; ++kt) {
      half4_t ph;
      ph[0] = (_Float16)st[kt][0]; ph[1] = (_Float16)st[kt][1];
      ph[2] = (_Float16)st[kt][2]; ph[3] = (_Float16)st[kt][3];
      *(half4_t*)(Pw + kt * 16 + quad * 4) = ph;
    }

    // rescale O rows (row index q' = 4*quad+r lives at source lane 4*quad+r)
    float a4[4];
#pragma unroll
    for (int r = 0; r < 4; ++r) a4[r] = __shfl(alpha, 4 * quad + r, 64);
#pragma unroll
    for (int nb = 0; nb < 4; ++nb)
#pragma unroll
      for (int r = 0; r < 4; ++r) O[nb][r] *= a4[r];

    // O += P * V : A = P[q][key] (m=q), B = V[key][d] from V^T rows
#pragma unroll
    for (int c = 0; c < 2; ++c) {
      half8_t pf = *(half8_t*)(Ps + w * 1152 + m * 72 + c * 32 + quad * 8);
#pragma unroll
      for (int nb = 0; nb < 4; ++nb) {
        half8_t vf = *(half8_t*)(Vt + (nb * 16 + m) * 72 + c * 32 + quad * 8);
        O[nb] = __builtin_amdgcn_mfma_f32_16x16x32_f16(pf, vf, O[nb], 0, 0, 0);
      }
    }
  }

  // epilogue: O / l  -> Os[q_local][d] -> coalesced AO store
  float l4[4];
#pragma unroll
  for (int r = 0; r < 4; ++r) l4[r] = __shfl(l_run, 4 * quad + r, 64);
  __syncthreads();  // everyone done with Ks/Vt/Ps before overwriting with Os
#pragma unroll
  for (int nb = 0; nb < 4; ++nb) {
#pragma unroll
    for (int r = 0; r < 4; ++r)
      Os[(w * 16 + 4 * quad + r) * 68 + nb * 16 + m] = O[nb][r] * (1.0f / l4[r]);
  }
  __syncthreads();
  const int ql = tid >> 2, dg = (tid & 3) * 16;
  const int b = bh >> 4, h = bh & 15;
  float* dst = AO + ((size_t)(b * NSEQ + q0 + ql)) * CDIM + h * DH + dg;
#pragma unroll
  for (int i = 0; i < 4; ++i)
    *(float4*)(dst + 4 * i) = *(float4*)&Os[ql * 68 + dg + 4 * i];
}

// ---------------------------------------------------------------------------
// Kernel 3: out = AO @ W_proj + b_proj (fp32, unchanged)
// ---------------------------------------------------------------------------
__global__ __launch_bounds__(256) void proj_kernel(
    const float* __restrict__ A, const float* __restrict__ W,
    const float* __restrict__ bias, float* __restrict__ out) {
  __shared__ float As[16][64];
  __shared__ float Bs[16][64];
  const int tid = threadIdx.x;
  const int tx = tid & 15, ty = tid >> 4;
  const int m0 = blockIdx.y * 64;
  const int n0 = blockIdx.x * 64;
  const int lr = tid >> 2;
  const int lc = (tid & 3) * 4;
  float acc[4][4] = {};
  const float* arow = A + (size_t)(m0 + lr) * CDIM + lc;
  const float* wrow = W + (size_t)ty * CDIM + n0 + tx * 4;

  for (int k0 = 0; k0 < CDIM; k0 += 16) {
    float4 a4 = *(const float4*)(arow + k0);
    float4 b4 = *(const float4*)(wrow + (size_t)k0 * CDIM);
    __syncthreads();
    As[lc + 0][lr] = a4.x; As[lc + 1][lr] = a4.y;
    As[lc + 2][lr] = a4.z; As[lc + 3][lr] = a4.w;
    *(float4*)&Bs[ty][tx * 4] = b4;
    __syncthreads();
#pragma unroll
    for (int kk = 0; kk < 16; ++kk) {
      float4 av = *(const float4*)&As[kk][ty * 4];
      float4 bv = *(const float4*)&Bs[kk][tx * 4];
      float a[4] = {av.x, av.y, av.z, av.w};
      float b[4] = {bv.x, bv.y, bv.z, bv.w};
#pragma unroll
      for (int i = 0; i < 4; ++i)
#pragma unroll
        for (int j = 0; j < 4; ++j) acc[i][j] += a[i] * b[j];
    }
  }
#pragma unroll
  for (int i = 0; i < 4; ++i) {
    const int mm = m0 + ty * 4 + i;
    float4 o4;
    o4.x = acc[i][0] + bias[n0 + tx * 4 + 0];
    o4.y = acc[i][1] + bias[n0 + tx * 4 + 1];
    o4.z = acc[i][2] + bias[n0 + tx * 4 + 2];
    o4.w = acc[i][3] + bias[n0 + tx * 4 + 3];
    *(float4*)&out[(size_t)mm * CDIM + n0 + tx * 4] = o4;
  }
}

// ---------------------------------------------------------------------------
extern "C" void kernel_launch(void* const* d_in, const int* in_sizes, int n_in,
                              void* d_out, int out_size, void* d_ws, size_t ws_size,
                              hipStream_t stream) {
  const float* x     = (const float*)d_in[0];
  const float* Wqkv  = (const float*)d_in[1];
  const float* bqkv  = (const float*)d_in[2];
  const float* Wproj = (const float*)d_in[3];
  const float* bproj = (const float*)d_in[4];
  float* out = (float*)d_out;

  const size_t per = (size_t)BSZ * NH * NSEQ * DH;  // 8,388,608 elements
  _Float16* Qh = (_Float16*)d_ws;
  _Float16* Kh = Qh + per;
  _Float16* Vh = Kh + per;
  float* AO = (float*)(Vh + per);   // [B,N,C] fp32

  qkv_rope_kernel<<<dim3(48, 128), 256, 0, stream>>>(x, Wqkv, bqkv, Qh, Kh, Vh);
  attn_kernel<<<dim3(32, 64), 256, 0, stream>>>(Qh, Kh, Vh, AO);
  proj_kernel<<<dim3(16, 128), 256, 0, stream>>>(AO, Wproj, bproj, out);
}

// Round 3
// 395.487 us; speedup vs baseline: 5.6623x; 2.9638x over previous
//
#include <hip/hip_runtime.h>
#include <hip/hip_bf16.h>
#include <math.h>

#define BSZ 4
#define NSEQ 2048
#define CDIM 1024
#define NH 16
#define DH 64
#define KC 64

typedef _Float16 half8_t __attribute__((ext_vector_type(8)));
typedef _Float16 half4_t __attribute__((ext_vector_type(4)));
typedef float floatx4 __attribute__((ext_vector_type(4)));

#define GLOBAL_AS(p) ((const __attribute__((address_space(1))) void*)(p))
#define LDS_AS(p)    ((__attribute__((address_space(3))) void*)(p))

// ---------------------------------------------------------------------------
// Prep kernels: fp32 -> fp16 casts (weights transposed to [N][K] for gemm_bt)
// ---------------------------------------------------------------------------
__global__ __launch_bounds__(256) void cast_x_kernel(
    const float* __restrict__ src, _Float16* __restrict__ dst) {
  const size_t i = ((size_t)blockIdx.x * 256 + threadIdx.x) * 8;
  float4 a = *(const float4*)(src + i);
  float4 b = *(const float4*)(src + i + 4);
  half8_t h;
  h[0] = (_Float16)a.x; h[1] = (_Float16)a.y; h[2] = (_Float16)a.z; h[3] = (_Float16)a.w;
  h[4] = (_Float16)b.x; h[5] = (_Float16)b.y; h[6] = (_Float16)b.z; h[7] = (_Float16)b.w;
  *(half8_t*)(dst + i) = h;
}

__global__ __launch_bounds__(256) void transpose_cast_kernel(
    const float* __restrict__ src, _Float16* __restrict__ dst, int R, int C) {
  __shared__ float Ls[64][65];
  const int t = threadIdx.x;
  const int r0 = blockIdx.y * 64, c0 = blockIdx.x * 64;
  {
    const int lr = t >> 2, lcg = (t & 3) * 16;
    const float* s = src + (size_t)(r0 + lr) * C + c0 + lcg;
#pragma unroll
    for (int u = 0; u < 4; ++u)
      *(float4*)&Ls[lr][lcg + 4 * u] = *(const float4*)(s + 4 * u);
  }
  __syncthreads();
  const int c = t >> 2, rg = (t & 3) * 16;
  half8_t h0, h1;
#pragma unroll
  for (int u = 0; u < 8; ++u) h0[u] = (_Float16)Ls[rg + u][c];
#pragma unroll
  for (int u = 0; u < 8; ++u) h1[u] = (_Float16)Ls[rg + 8 + u][c];
  _Float16* d = dst + (size_t)(c0 + c) * R + r0 + rg;
  *(half8_t*)d = h0;
  *(half8_t*)(d + 8) = h1;
}

// ---------------------------------------------------------------------------
// Kernel 1: QKV GEMM (fp16 MFMA, 128x128 tile, BK=64) + bias + RoPE epilogue.
// A = xh [8192][1024], B = Wt [3072][1024] (B^T). Wave w: 64x64 subtile;
// its 64 cols = one full head, so the RoPE partner (d +/- 32) is acc[mt][nt^2]
// in the SAME lane's registers -- no LDS needed.
// Outputs fp16: Qh [bh][n][64] (x 0.125*log2e), Kh [bh][n][64], Vh [bh][d][n].
// ---------------------------------------------------------------------------
__global__ __launch_bounds__(256) void qkv_gemm_kernel(
    const _Float16* __restrict__ xh, const _Float16* __restrict__ Wt,
    const float* __restrict__ bias, _Float16* __restrict__ Qh,
    _Float16* __restrict__ Kh, _Float16* __restrict__ Vh) {
  __shared__ _Float16 As[128 * 64];
  __shared__ _Float16 Bs[128 * 64];
  const int tid = threadIdx.x;
  const int lane = tid & 63, w = tid >> 6;
  const int m = lane & 15, quad = lane >> 4;
  const int wr = (w >> 1) * 64, wc = (w & 1) * 64;
  const int m0 = blockIdx.y * 128;
  const int N0 = blockIdx.x * 128;
  const int sr = lane >> 3, sc = (lane & 7) * 8;

  floatx4 acc[4][4];
#pragma unroll
  for (int i = 0; i < 4; ++i)
#pragma unroll
    for (int j = 0; j < 4; ++j) acc[i][j] = (floatx4){0.f, 0.f, 0.f, 0.f};

  for (int k0 = 0; k0 < CDIM; k0 += 64) {
    __syncthreads();
#pragma unroll
    for (int i = 0; i < 4; ++i) {
      const int row = (w * 4 + i) * 8 + sr;
      __builtin_amdgcn_global_load_lds(
          GLOBAL_AS(xh + (size_t)(m0 + row) * CDIM + k0 + sc),
          LDS_AS(As + (w * 4 + i) * 512), 16, 0, 0);
      __builtin_amdgcn_global_load_lds(
          GLOBAL_AS(Wt + (size_t)(N0 + row) * CDIM + k0 + sc),
          LDS_AS(Bs + (w * 4 + i) * 512), 16, 0, 0);
    }
    __syncthreads();
#pragma unroll
    for (int ks = 0; ks < 2; ++ks) {
      half8_t af[4], bf[4];
#pragma unroll
      for (int mt = 0; mt < 4; ++mt)
        af[mt] = *(half8_t*)(As + (wr + mt * 16 + m) * 64 + ks * 32 + quad * 8);
#pragma unroll
      for (int nt = 0; nt < 4; ++nt)
        bf[nt] = *(half8_t*)(Bs + (wc + nt * 16 + m) * 64 + ks * 32 + quad * 8);
#pragma unroll
      for (int mt = 0; mt < 4; ++mt)
#pragma unroll
        for (int nt = 0; nt < 4; ++nt)
          acc[mt][nt] = __builtin_amdgcn_mfma_f32_16x16x32_f16(
              af[mt], bf[nt], acc[mt][nt], 0, 0, 0);
    }
  }

  // epilogue
  const int F0 = N0 + wc;            // wave's feature base (multiple of 64)
  const int which = F0 >> 10;        // 0=q 1=k 2=v
  const int head = (F0 & 1023) >> 6;
  float bv[4];
#pragma unroll
  for (int nt = 0; nt < 4; ++nt) bv[nt] = bias[F0 + nt * 16 + m];

  if (which == 2) {
#pragma unroll
    for (int mt = 0; mt < 4; ++mt)
#pragma unroll
      for (int reg = 0; reg < 4; ++reg) {
        const int gm = m0 + wr + mt * 16 + 4 * quad + reg;
        const int b = gm >> 11, n = gm & 2047;
        const size_t vbase = ((size_t)(b * NH + head) * DH) * NSEQ + n;
#pragma unroll
        for (int nt = 0; nt < 4; ++nt)
          Vh[vbase + (size_t)(nt * 16 + m) * NSEQ] =
              (_Float16)(acc[mt][nt][reg] + bv[nt]);
      }
  } else {
    _Float16* dst = which ? Kh : Qh;
    const float qs = which ? 1.0f : 0.125f * 1.4426950408889634f;
    const float invfA = expf(-9.210340371976184f * ((float)m * (1.0f / 32.0f)));
    const float invfB = expf(-9.210340371976184f * ((float)(16 + m) * (1.0f / 32.0f)));
#pragma unroll
    for (int mt = 0; mt < 4; ++mt)
#pragma unroll
      for (int reg = 0; reg < 4; ++reg) {
        const int gm = m0 + wr + mt * 16 + 4 * quad + reg;
        const int b = gm >> 11, n = gm & 2047;
        float sA, cA, sB, cB;
        sincosf((float)n * invfA, &sA, &cA);
        sincosf((float)n * invfB, &sB, &cB);
        const size_t obase = ((size_t)(b * NH + head) * NSEQ + n) * DH;
#pragma unroll
        for (int nt = 0; nt < 4; ++nt) {
          const float val = acc[mt][nt][reg] + bv[nt];
          const float rot = (nt < 2) ? -(acc[mt][nt + 2][reg] + bv[nt + 2])
                                     :  (acc[mt][nt - 2][reg] + bv[nt - 2]);
          const float sv = (nt & 1) ? sB : sA;
          const float cv = (nt & 1) ? cB : cA;
          dst[obase + nt * 16 + m] = (_Float16)((val * cv + rot * sv) * qs);
        }
      }
  }
}

// ---------------------------------------------------------------------------
// Kernel 2: flash attention, fp16 MFMA (unchanged except fp16 AO output).
// ---------------------------------------------------------------------------
__global__ __launch_bounds__(256) void attn_kernel(
    const _Float16* __restrict__ Qh, const _Float16* __restrict__ Kh,
    const _Float16* __restrict__ Vh, _Float16* __restrict__ AO) {
  __shared__ char smem[27648];
  _Float16* Ks = (_Float16*)smem;            // [64][72]
  _Float16* Vt = (_Float16*)(smem + 9216);   // [64][72] (rows = d)
  _Float16* Ps = (_Float16*)(smem + 18432);  // [4][16][72]
  float* Os = (float*)smem;                  // [64][68] (epilogue reuse)

  const int tid = threadIdx.x;
  const int lane = tid & 63;
  const int w = tid >> 6;
  const int m = lane & 15;
  const int quad = lane >> 4;
  const int bh = blockIdx.y;
  const int q0 = blockIdx.x * 64;

  const _Float16* Qb = Qh + (size_t)bh * NSEQ * DH;
  const _Float16* Kb = Kh + (size_t)bh * NSEQ * DH;
  const _Float16* Vb = Vh + (size_t)bh * DH * NSEQ;

  const int qrow = q0 + w * 16 + m;
  half8_t qf0 = *(const half8_t*)(Qb + (size_t)qrow * DH + quad * 8);
  half8_t qf1 = *(const half8_t*)(Qb + (size_t)qrow * DH + 32 + quad * 8);

  float m_run = -1e30f, l_run = 0.0f;
  floatx4 O[4];
#pragma unroll
  for (int nb = 0; nb < 4; ++nb) O[nb] = (floatx4){0.f, 0.f, 0.f, 0.f};

  for (int ck = 0; ck < NSEQ / KC; ++ck) {
    const int k0 = ck * KC;
    __syncthreads();
    {
      const _Float16* Kc = Kb + (size_t)k0 * DH;
      const _Float16* Vc = Vb + k0;
      int g = tid;
      int key = g >> 3, dg = g & 7;
      *(half8_t*)(Ks + key * 72 + dg * 8) = *(const half8_t*)(Kc + key * 64 + dg * 8);
      *(half8_t*)(Vt + key * 72 + dg * 8) = *(const half8_t*)(Vc + (size_t)key * NSEQ + dg * 8);
      g = tid + 256;
      key = g >> 3; dg = g & 7;
      *(half8_t*)(Ks + key * 72 + dg * 8) = *(const half8_t*)(Kc + key * 64 + dg * 8);
      *(half8_t*)(Vt + key * 72 + dg * 8) = *(const half8_t*)(Vc + (size_t)key * NSEQ + dg * 8);
    }
    __syncthreads();

    floatx4 st[4];
#pragma unroll
    for (int kt = 0; kt < 4; ++kt) {
      floatx4 a = (floatx4){0.f, 0.f, 0.f, 0.f};
      half8_t kf0 = *(half8_t*)(Ks + (kt * 16 + m) * 72 + quad * 8);
      half8_t kf1 = *(half8_t*)(Ks + (kt * 16 + m) * 72 + 32 + quad * 8);
      a = __builtin_amdgcn_mfma_f32_16x16x32_f16(kf0, qf0, a, 0, 0, 0);
      a = __builtin_amdgcn_mfma_f32_16x16x32_f16(kf1, qf1, a, 0, 0, 0);
      st[kt] = a;
    }

    float mx = -1e30f;
#pragma unroll
    for (int kt = 0; kt < 4; ++kt)
#pragma unroll
      for (int r = 0; r < 4; ++r) mx = fmaxf(mx, st[kt][r]);
    mx = fmaxf(mx, __shfl_xor(mx, 16, 64));
    mx = fmaxf(mx, __shfl_xor(mx, 32, 64));
    const float m_new = fmaxf(m_run, mx);
    const float alpha = __builtin_exp2f(m_run - m_new);
    m_run = m_new;
    float rs = 0.0f;
#pragma unroll
    for (int kt = 0; kt < 4; ++kt)
#pragma unroll
      for (int r = 0; r < 4; ++r) {
        const float pv = __builtin_exp2f(st[kt][r] - m_new);
        st[kt][r] = pv;
        rs += pv;
      }
    rs += __shfl_xor(rs, 16, 64);
    rs += __shfl_xor(rs, 32, 64);
    l_run = l_run * alpha + rs;

    _Float16* Pw = Ps + w * 1152 + m * 72;
#pragma unroll
    for (int kt = 0; kt < 4; ++kt) {
      half4_t ph;
      ph[0] = (_Float16)st[kt][0]; ph[1] = (_Float16)st[kt][1];
      ph[2] = (_Float16)st[kt][2]; ph[3] = (_Float16)st[kt][3];
      *(half4_t*)(Pw + kt * 16 + quad * 4) = ph;
    }

    float a4[4];
#pragma unroll
    for (int r = 0; r < 4; ++r) a4[r] = __shfl(alpha, 4 * quad + r, 64);
#pragma unroll
    for (int nb = 0; nb < 4; ++nb)
#pragma unroll
      for (int r = 0; r < 4; ++r) O[nb][r] *= a4[r];

#pragma unroll
    for (int c = 0; c < 2; ++c) {
      half8_t pf = *(half8_t*)(Ps + w * 1152 + m * 72 + c * 32 + quad * 8);
#pragma unroll
      for (int nb = 0; nb < 4; ++nb) {
        half8_t vf = *(half8_t*)(Vt + (nb * 16 + m) * 72 + c * 32 + quad * 8);
        O[nb] = __builtin_amdgcn_mfma_f32_16x16x32_f16(pf, vf, O[nb], 0, 0, 0);
      }
    }
  }

  float l4[4];
#pragma unroll
  for (int r = 0; r < 4; ++r) l4[r] = __shfl(l_run, 4 * quad + r, 64);
  __syncthreads();
#pragma unroll
  for (int nb = 0; nb < 4; ++nb) {
#pragma unroll
    for (int r = 0; r < 4; ++r)
      Os[(w * 16 + 4 * quad + r) * 68 + nb * 16 + m] = O[nb][r] * (1.0f / l4[r]);
  }
  __syncthreads();
  const int ql = tid >> 2, dg = (tid & 3) * 16;
  const int b = bh >> 4, h = bh & 15;
  half8_t o0, o1;
#pragma unroll
  for (int u = 0; u < 8; ++u) o0[u] = (_Float16)Os[ql * 68 + dg + u];
#pragma unroll
  for (int u = 0; u < 8; ++u) o1[u] = (_Float16)Os[ql * 68 + dg + 8 + u];
  _Float16* dst = AO + ((size_t)(b * NSEQ + q0 + ql)) * CDIM + h * DH + dg;
  *(half8_t*)dst = o0;
  *(half8_t*)(dst + 8) = o1;
}

// ---------------------------------------------------------------------------
// Kernel 3: proj GEMM (fp16 MFMA) + bias, fp32 out.
// A = AOh [8192][1024], B = Wpt [1024][1024] (B^T).
// ---------------------------------------------------------------------------
__global__ __launch_bounds__(256) void proj_gemm_kernel(
    const _Float16* __restrict__ Ah, const _Float16* __restrict__ Wt,
    const float* __restrict__ bias, float* __restrict__ out) {
  __shared__ _Float16 As[128 * 64];
  __shared__ _Float16 Bs[128 * 64];
  const int tid = threadIdx.x;
  const int lane = tid & 63, w = tid >> 6;
  const int m = lane & 15, quad = lane >> 4;
  const int wr = (w >> 1) * 64, wc = (w & 1) * 64;
  const int m0 = blockIdx.y * 128;
  const int N0 = blockIdx.x * 128;
  const int sr = lane >> 3, sc = (lane & 7) * 8;

  floatx4 acc[4][4];
#pragma unroll
  for (int i = 0; i < 4; ++i)
#pragma unroll
    for (int j = 0; j < 4; ++j) acc[i][j] = (floatx4){0.f, 0.f, 0.f, 0.f};

  for (int k0 = 0; k0 < CDIM; k0 += 64) {
    __syncthreads();
#pragma unroll
    for (int i = 0; i < 4; ++i) {
      const int row = (w * 4 + i) * 8 + sr;
      __builtin_amdgcn_global_load_lds(
          GLOBAL_AS(Ah + (size_t)(m0 + row) * CDIM + k0 + sc),
          LDS_AS(As + (w * 4 + i) * 512), 16, 0, 0);
      __builtin_amdgcn_global_load_lds(
          GLOBAL_AS(Wt + (size_t)(N0 + row) * CDIM + k0 + sc),
          LDS_AS(Bs + (w * 4 + i) * 512), 16, 0, 0);
    }
    __syncthreads();
#pragma unroll
    for (int ks = 0; ks < 2; ++ks) {
      half8_t af[4], bf[4];
#pragma unroll
      for (int mt = 0; mt < 4; ++mt)
        af[mt] = *(half8_t*)(As + (wr + mt * 16 + m) * 64 + ks * 32 + quad * 8);
#pragma unroll
      for (int nt = 0; nt < 4; ++nt)
        bf[nt] = *(half8_t*)(Bs + (wc + nt * 16 + m) * 64 + ks * 32 + quad * 8);
#pragma unroll
      for (int mt = 0; mt < 4; ++mt)
#pragma unroll
        for (int nt = 0; nt < 4; ++nt)
          acc[mt][nt] = __builtin_amdgcn_mfma_f32_16x16x32_f16(
              af[mt], bf[nt], acc[mt][nt], 0, 0, 0);
    }
  }

  const int F0 = N0 + wc;
  float bv[4];
#pragma unroll
  for (int nt = 0; nt < 4; ++nt) bv[nt] = bias[F0 + nt * 16 + m];
#pragma unroll
  for (int mt = 0; mt < 4; ++mt)
#pragma unroll
    for (int reg = 0; reg < 4; ++reg) {
      const int gm = m0 + wr + mt * 16 + 4 * quad + reg;
#pragma unroll
      for (int nt = 0; nt < 4; ++nt)
        out[(size_t)gm * CDIM + F0 + nt * 16 + m] = acc[mt][nt][reg] + bv[nt];
    }
}

// ---------------------------------------------------------------------------
extern "C" void kernel_launch(void* const* d_in, const int* in_sizes, int n_in,
                              void* d_out, int out_size, void* d_ws, size_t ws_size,
                              hipStream_t stream) {
  const float* x     = (const float*)d_in[0];
  const float* Wqkv  = (const float*)d_in[1];
  const float* bqkv  = (const float*)d_in[2];
  const float* Wproj = (const float*)d_in[3];
  const float* bproj = (const float*)d_in[4];
  float* out = (float*)d_out;

  const size_t per = (size_t)BSZ * NH * NSEQ * DH;  // 8,388,608
  _Float16* xh  = (_Float16*)d_ws;
  _Float16* Wt  = xh + per;                 // [3072][1024]
  _Float16* Wpt = Wt + (size_t)3072 * 1024; // [1024][1024]
  _Float16* Qh  = Wpt + (size_t)1024 * 1024;
  _Float16* Kh  = Qh + per;
  _Float16* Vh  = Kh + per;
  _Float16* AOh = Vh + per;

  cast_x_kernel<<<4096, 256, 0, stream>>>(x, xh);
  transpose_cast_kernel<<<dim3(48, 16), 256, 0, stream>>>(Wqkv, Wt, 1024, 3072);
  transpose_cast_kernel<<<dim3(16, 16), 256, 0, stream>>>(Wproj, Wpt, 1024, 1024);
  qkv_gemm_kernel<<<dim3(24, 64), 256, 0, stream>>>(xh, Wt, bqkv, Qh, Kh, Vh);
  attn_kernel<<<dim3(32, 64), 256, 0, stream>>>(Qh, Kh, Vh, AOh);
  proj_gemm_kernel<<<dim3(8, 64), 256, 0, stream>>>(AOh, Wpt, bproj, out);
}